// Round 2
// baseline (121.998 us; speedup 1.0000x reference)
//
#include <hip/hip_runtime.h>

// NCC loss, fused single-pass. Round 9: minimize HBM bytes via BH 8 -> 32.
// R8 post-mortem: harness ws-poison (2x256MiB fills, ~84us fixed, 80% HBM
// peak) sweeps L3 every iteration -> ncc_main reads are HBM-cold -> kernel
// is HBM-BYTE-bound. Bytes = inputs x (BH+8)/BH halo amplification:
//   BH=8: 128MB (R8, regressed), BH=16: 96MB (R7), BH=32: 84MB (this).
// Occupancy drops to 2 waves/CU but VALU time (~5.7us/wave) << BW time
// (~13.3us) so still BW-bound; ring widened 10 -> 12 buffers (4-row
// lookahead ~ 1600 VALU cyc > ~900 cy HBM latency) to keep loads covered.
//  - 1 wave = band of BH=32 rows x 512 cols (8 cols/lane). 40 rows/band.
//  - 12 rotating raw-row register buffers (static names, straight-line):
//    each row loaded ONCE; 4-output load lookahead.
//  - Branch-free: clamped row + 0/1 mask applied at accumulate time.
//  - 512 single-wave blocks, no barriers; shuffles for horizontal halo.

#define W 512
#define H 512
#define BH 32
#define NBANDS (H / BH)      // 16
#define NT 64

__device__ __forceinline__ float4 ld4(const float* p) {
    return *reinterpret_cast<const float4*>(p);
}

#define DECLBUF(P) float4 P##A0, P##A1, P##B0, P##B1; float P##m

// Load row y0+DR (clamped) raw into buffer P; mask 0/1. No use of data here
// -> no waitcnt until PADD consumes it.
#define LOADR(P, DR) do {                                                    \
    int _r  = y0 + (DR);                                                     \
    int _rc = _r < 0 ? 0 : (_r > (H - 1) ? (H - 1) : _r);                    \
    const float* _ip = Ip + _rc * W + x0;                                    \
    const float* _jp = Jp + _rc * W + x0;                                    \
    P##A0 = ld4(_ip);  P##A1 = ld4(_ip + 4);                                 \
    P##B0 = ld4(_jp);  P##B1 = ld4(_jp + 4);                                 \
    P##m  = (_r == _rc) ? 1.f : 0.f;                                         \
} while (0)

// v += masked row products. am = m*a; am*a = m*a*a (m in {0,1}).
#define PBODY(P, OP)                                                         \
    do {                                                                     \
        float _m = P##m;                                                     \
        float _a0=P##A0.x*_m, _a1=P##A0.y*_m, _a2=P##A0.z*_m, _a3=P##A0.w*_m;\
        float _a4=P##A1.x*_m, _a5=P##A1.y*_m, _a6=P##A1.z*_m, _a7=P##A1.w*_m;\
        float _b0=P##B0.x*_m, _b1=P##B0.y*_m, _b2=P##B0.z*_m, _b3=P##B0.w*_m;\
        float _b4=P##B1.x*_m, _b5=P##B1.y*_m, _b6=P##B1.z*_m, _b7=P##B1.w*_m;\
        v0[0] OP _a0; v0[1] OP _a1; v0[2] OP _a2; v0[3] OP _a3;              \
        v0[4] OP _a4; v0[5] OP _a5; v0[6] OP _a6; v0[7] OP _a7;              \
        v1[0] OP _b0; v1[1] OP _b1; v1[2] OP _b2; v1[3] OP _b3;              \
        v1[4] OP _b4; v1[5] OP _b5; v1[6] OP _b6; v1[7] OP _b7;              \
        v2[0] OP _a0*P##A0.x; v2[1] OP _a1*P##A0.y; v2[2] OP _a2*P##A0.z; v2[3] OP _a3*P##A0.w; \
        v2[4] OP _a4*P##A1.x; v2[5] OP _a5*P##A1.y; v2[6] OP _a6*P##A1.z; v2[7] OP _a7*P##A1.w; \
        v3[0] OP _b0*P##B0.x; v3[1] OP _b1*P##B0.y; v3[2] OP _b2*P##B0.z; v3[3] OP _b3*P##B0.w; \
        v3[4] OP _b4*P##B1.x; v3[5] OP _b5*P##B1.y; v3[6] OP _b6*P##B1.z; v3[7] OP _b7*P##B1.w; \
        v4[0] OP _a0*P##B0.x; v4[1] OP _a1*P##B0.y; v4[2] OP _a2*P##B0.z; v4[3] OP _a3*P##B0.w; \
        v4[4] OP _a4*P##B1.x; v4[5] OP _a5*P##B1.y; v4[6] OP _a6*P##B1.z; v4[7] OP _a7*P##B1.w; \
    } while (0)

#define PADD(P) PBODY(P, +=)
#define PSUB(P) PBODY(P, -=)

// Horizontal 9-sum, lo half (cols 0..3 of this lane); exports l7 for hi.
#define HLO(vv, h, l7out) do {                                               \
    float _l4 = __shfl_up(vv[4], 1), _l5 = __shfl_up(vv[5], 1);              \
    float _l6 = __shfl_up(vv[6], 1), _l7 = __shfl_up(vv[7], 1);              \
    if (lane == 0) { _l4 = 0.f; _l5 = 0.f; _l6 = 0.f; _l7 = 0.f; }           \
    float _t = (((_l4+_l5)+(_l6+_l7)) + ((vv[0]+vv[1])+(vv[2]+vv[3]))) + vv[4]; \
    h[0] = _t;                                                               \
    _t += vv[5] - _l4; h[1] = _t;                                            \
    _t += vv[6] - _l5; h[2] = _t;                                            \
    _t += vv[7] - _l6; h[3] = _t;                                            \
    l7out = _l7;                                                             \
} while (0)

// Horizontal 9-sum, hi half (cols 4..7), chained from h3/l7.
#define HHI(vv, h3in, l7in, h) do {                                          \
    float _r0 = __shfl_down(vv[0], 1), _r1 = __shfl_down(vv[1], 1);          \
    float _r2 = __shfl_down(vv[2], 1), _r3 = __shfl_down(vv[3], 1);          \
    if (lane == 63) { _r0 = 0.f; _r1 = 0.f; _r2 = 0.f; _r3 = 0.f; }          \
    float _t = (h3in) + _r0 - (l7in); h[0] = _t;                             \
    _t += _r1 - vv[0]; h[1] = _t;                                            \
    _t += _r2 - vv[1]; h[2] = _t;                                            \
    _t += _r3 - vv[2]; h[3] = _t;                                            \
} while (0)

#define CC4(h0a, h1a, h2a, h3a, h4a) do {                                    \
    _Pragma("unroll")                                                        \
    for (int _c = 0; _c < 4; ++_c) {                                         \
        float _Is = h0a[_c], _Js = h1a[_c];                                  \
        float _u  = _Is * inv81;                                             \
        float _cr = h4a[_c] - _u * _Js;                                      \
        float _Iv = h2a[_c] - _u * _Is;                                      \
        float _Jv = h3a[_c] - (_Js * inv81) * _Js;                           \
        cc_acc += (_cr * _cr) * __builtin_amdgcn_rcpf(_Iv * _Jv + 1e-6f);    \
    }                                                                        \
} while (0)

#define EPI() do {                                                           \
    float h0[4], h1[4], h2[4], h3[4], h4[4];                                 \
    float s0, s1, s2, s3, s4;                                                \
    HLO(v0, h0, s0); HLO(v1, h1, s1); HLO(v2, h2, s2);                       \
    HLO(v3, h3, s3); HLO(v4, h4, s4);                                        \
    CC4(h0, h1, h2, h3, h4);                                                 \
    float e0 = h0[3], e1 = h1[3], e2 = h2[3], e3 = h3[3], e4 = h4[3];        \
    HHI(v0, e0, s0, h0); HHI(v1, e1, s1, h1); HHI(v2, e2, s2, h2);           \
    HHI(v3, e3, s3, h3); HHI(v4, e4, s4, h4);                                \
    CC4(h0, h1, h2, h3, h4);                                                 \
} while (0)

// One output row: add new bottom row, epilogue, drop top row (register-
// resident since its load), optionally load a future row into freed slot.
#define STEPL(AB, SB, DR) do { PADD(AB); EPI(); PSUB(SB); LOADR(SB, DR); } while (0)
#define STEPN(AB, SB)     do { PADD(AB); EPI(); PSUB(SB); } while (0)

__global__ __launch_bounds__(NT)
void ncc_main(const float* __restrict__ I, const float* __restrict__ J,
              float* __restrict__ partials) {
    const int lane = threadIdx.x & 63;

    // XCD swizzle: each XCD gets a contiguous band range (halo rows in L2).
    const int nblk = gridDim.x;            // 512, divisible by 8
    const int g = (blockIdx.x & 7) * (nblk >> 3) + (blockIdx.x >> 3);

    const int b    = g >> 4;               // g / NBANDS
    const int band = g & (NBANDS - 1);
    const int y0   = band * BH;
    const float* Ip = I + (size_t)b * (H * W);
    const float* Jp = J + (size_t)b * (H * W);
    const int x0 = lane * 8;

    float v0[8], v1[8], v2[8], v3[8], v4[8];
    #pragma unroll
    for (int k = 0; k < 8; ++k) { v0[k]=0.f; v1[k]=0.f; v2[k]=0.f; v3[k]=0.f; v4[k]=0.f; }

    float cc_acc = 0.f;
    const float inv81 = 1.f / 81.f;

    DECLBUF(B0); DECLBUF(B1); DECLBUF(B2);  DECLBUF(B3);
    DECLBUF(B4); DECLBUF(B5); DECLBUF(B6);  DECLBUF(B7);
    DECLBUF(B8); DECLBUF(B9); DECLBUF(B10); DECLBUF(B11);

    // Prologue: issue 12 rows' loads back-to-back (rows y0-4 .. y0+7).
    LOADR(B0, -4); LOADR(B1, -3); LOADR(B2,   -2); LOADR(B3,  -1);
    LOADR(B4,  0); LOADR(B5,  1); LOADR(B6,    2); LOADR(B7,   3);
    LOADR(B8,  4); LOADR(B9,  5); LOADR(B10,   6); LOADR(B11,  7);

    // Prime vertical window with rows y0-4 .. y0+3.
    PADD(B0); PADD(B1); PADD(B2); PADD(B3);
    PADD(B4); PADD(B5); PADD(B6); PADD(B7);

    // 32 output rows. Slot of row r (k=r+4): k%12. Sub slot == next load slot
    // (4-row lookahead: row 8+i loaded at step i, consumed at step i+4).
    STEPL(B8,  B0,   8);   // i=0 : +row4  -row-4  load row8
    STEPL(B9,  B1,   9);   // i=1
    STEPL(B10, B2,  10);   // i=2
    STEPL(B11, B3,  11);   // i=3
    STEPL(B0,  B4,  12);   // i=4
    STEPL(B1,  B5,  13);   // i=5
    STEPL(B2,  B6,  14);   // i=6
    STEPL(B3,  B7,  15);   // i=7
    STEPL(B4,  B8,  16);   // i=8
    STEPL(B5,  B9,  17);   // i=9
    STEPL(B6,  B10, 18);   // i=10
    STEPL(B7,  B11, 19);   // i=11
    STEPL(B8,  B0,  20);   // i=12
    STEPL(B9,  B1,  21);   // i=13
    STEPL(B10, B2,  22);   // i=14
    STEPL(B11, B3,  23);   // i=15
    STEPL(B0,  B4,  24);   // i=16
    STEPL(B1,  B5,  25);   // i=17
    STEPL(B2,  B6,  26);   // i=18
    STEPL(B3,  B7,  27);   // i=19
    STEPL(B4,  B8,  28);   // i=20
    STEPL(B5,  B9,  29);   // i=21
    STEPL(B6,  B10, 30);   // i=22
    STEPL(B7,  B11, 31);   // i=23
    STEPL(B8,  B0,  32);   // i=24
    STEPL(B9,  B1,  33);   // i=25
    STEPL(B10, B2,  34);   // i=26
    STEPL(B11, B3,  35);   // i=27
    STEPN(B0,  B4);        // i=28
    STEPN(B1,  B5);        // i=29
    STEPN(B2,  B6);        // i=30
    STEPN(B3,  B7);        // i=31

    // Single-wave block: shuffle reduce, lane 0 writes the partial.
    #pragma unroll
    for (int off = 32; off > 0; off >>= 1)
        cc_acc += __shfl_down(cc_acc, off, 64);
    if (lane == 0) partials[blockIdx.x] = cc_acc;
}

__global__ __launch_bounds__(256)
void ncc_finish(const float* __restrict__ partials, float* __restrict__ out,
                int n, float inv_total) {
    float v = 0.f;
    for (int i = threadIdx.x; i < n; i += blockDim.x) v += partials[i];
    #pragma unroll
    for (int off = 32; off > 0; off >>= 1)
        v += __shfl_down(v, off, 64);
    __shared__ float wsum[4];
    if ((threadIdx.x & 63) == 0) wsum[threadIdx.x >> 6] = v;
    __syncthreads();
    if (threadIdx.x == 0) {
        float t = (wsum[0] + wsum[1]) + (wsum[2] + wsum[3]);
        out[0] = 1.0f - t * inv_total;
    }
}

extern "C" void kernel_launch(void* const* d_in, const int* in_sizes, int n_in,
                              void* d_out, int out_size, void* d_ws, size_t ws_size,
                              hipStream_t stream) {
    const float* I = (const float*)d_in[0];   // predict
    const float* J = (const float*)d_in[1];   // target
    float* out = (float*)d_out;
    float* partials = (float*)d_ws;           // nblocks floats (2 KB)

    const int n = in_sizes[0];                // B*1*H*W
    const int B = n / (H * W);
    const int nblocks = B * NBANDS;           // 512 for B=32

    ncc_main<<<nblocks, NT, 0, stream>>>(I, J, partials);
    ncc_finish<<<1, 256, 0, stream>>>(partials, out, nblocks, 1.0f / (float)n);
}

// Round 3
// 104.179 us; speedup vs baseline: 1.1710x; 1.1710x over previous
//
#include <hip/hip_runtime.h>

// NCC loss, fused single-pass. Round 10: R7 geometry + lift VGPR clamp.
// R9 post-mortem: steady-state ncc_main has ~ZERO HBM bytes (inputs stay
// L3-resident across iterations; the 2x256MiB ws-poison fills do NOT evict
// them) -> kernel is LATENCY-bound, not byte-bound. VGPR_Count=148 showed
// the compiler clamped registers (no min-waves hint) and sank the ring
// loads toward their uses, collapsing the lookahead -> exposed ~500cy L3
// latency per row. Fix: back to best-known BH=16 / 1024 blocks (4 waves/CU)
// and __launch_bounds__(64, 1) so the 10-row ring (~235 VGPR <= 256 cap)
// stays register-resident with hoisted loads. HW still fits 2 waves/SIMD
// at this VGPR count, and the grid only needs 1/SIMD.
//  - 1 wave = band of BH=16 rows x 512 cols (8 cols/lane). 24 rows/band.
//  - 10 rotating raw-row register buffers (static names, straight-line):
//    each row loaded ONCE; 2-output load lookahead (~1280 cy > L3 latency).
//  - Branch-free: clamped row + 0/1 mask applied at accumulate time.
//  - 1024 single-wave blocks, no barriers; shuffles for horizontal halo.

#define W 512
#define H 512
#define BH 16
#define NBANDS (H / BH)      // 32
#define NT 64

__device__ __forceinline__ float4 ld4(const float* p) {
    return *reinterpret_cast<const float4*>(p);
}

#define DECLBUF(P) float4 P##A0, P##A1, P##B0, P##B1; float P##m

// Load row y0+DR (clamped) raw into buffer P; mask 0/1. No use of data here
// -> no waitcnt until PADD consumes it.
#define LOADR(P, DR) do {                                                    \
    int _r  = y0 + (DR);                                                     \
    int _rc = _r < 0 ? 0 : (_r > (H - 1) ? (H - 1) : _r);                    \
    const float* _ip = Ip + _rc * W + x0;                                    \
    const float* _jp = Jp + _rc * W + x0;                                    \
    P##A0 = ld4(_ip);  P##A1 = ld4(_ip + 4);                                 \
    P##B0 = ld4(_jp);  P##B1 = ld4(_jp + 4);                                 \
    P##m  = (_r == _rc) ? 1.f : 0.f;                                         \
} while (0)

// v += masked row products. am = m*a; am*a = m*a*a (m in {0,1}).
#define PBODY(P, OP)                                                         \
    do {                                                                     \
        float _m = P##m;                                                     \
        float _a0=P##A0.x*_m, _a1=P##A0.y*_m, _a2=P##A0.z*_m, _a3=P##A0.w*_m;\
        float _a4=P##A1.x*_m, _a5=P##A1.y*_m, _a6=P##A1.z*_m, _a7=P##A1.w*_m;\
        float _b0=P##B0.x*_m, _b1=P##B0.y*_m, _b2=P##B0.z*_m, _b3=P##B0.w*_m;\
        float _b4=P##B1.x*_m, _b5=P##B1.y*_m, _b6=P##B1.z*_m, _b7=P##B1.w*_m;\
        v0[0] OP _a0; v0[1] OP _a1; v0[2] OP _a2; v0[3] OP _a3;              \
        v0[4] OP _a4; v0[5] OP _a5; v0[6] OP _a6; v0[7] OP _a7;              \
        v1[0] OP _b0; v1[1] OP _b1; v1[2] OP _b2; v1[3] OP _b3;              \
        v1[4] OP _b4; v1[5] OP _b5; v1[6] OP _b6; v1[7] OP _b7;              \
        v2[0] OP _a0*P##A0.x; v2[1] OP _a1*P##A0.y; v2[2] OP _a2*P##A0.z; v2[3] OP _a3*P##A0.w; \
        v2[4] OP _a4*P##A1.x; v2[5] OP _a5*P##A1.y; v2[6] OP _a6*P##A1.z; v2[7] OP _a7*P##A1.w; \
        v3[0] OP _b0*P##B0.x; v3[1] OP _b1*P##B0.y; v3[2] OP _b2*P##B0.z; v3[3] OP _b3*P##B0.w; \
        v3[4] OP _b4*P##B1.x; v3[5] OP _b5*P##B1.y; v3[6] OP _b6*P##B1.z; v3[7] OP _b7*P##B1.w; \
        v4[0] OP _a0*P##B0.x; v4[1] OP _a1*P##B0.y; v4[2] OP _a2*P##B0.z; v4[3] OP _a3*P##B0.w; \
        v4[4] OP _a4*P##B1.x; v4[5] OP _a5*P##B1.y; v4[6] OP _a6*P##B1.z; v4[7] OP _a7*P##B1.w; \
    } while (0)

#define PADD(P) PBODY(P, +=)
#define PSUB(P) PBODY(P, -=)

// Horizontal 9-sum, lo half (cols 0..3 of this lane); exports l7 for hi.
#define HLO(vv, h, l7out) do {                                               \
    float _l4 = __shfl_up(vv[4], 1), _l5 = __shfl_up(vv[5], 1);              \
    float _l6 = __shfl_up(vv[6], 1), _l7 = __shfl_up(vv[7], 1);              \
    if (lane == 0) { _l4 = 0.f; _l5 = 0.f; _l6 = 0.f; _l7 = 0.f; }           \
    float _t = (((_l4+_l5)+(_l6+_l7)) + ((vv[0]+vv[1])+(vv[2]+vv[3]))) + vv[4]; \
    h[0] = _t;                                                               \
    _t += vv[5] - _l4; h[1] = _t;                                            \
    _t += vv[6] - _l5; h[2] = _t;                                            \
    _t += vv[7] - _l6; h[3] = _t;                                            \
    l7out = _l7;                                                             \
} while (0)

// Horizontal 9-sum, hi half (cols 4..7), chained from h3/l7.
#define HHI(vv, h3in, l7in, h) do {                                          \
    float _r0 = __shfl_down(vv[0], 1), _r1 = __shfl_down(vv[1], 1);          \
    float _r2 = __shfl_down(vv[2], 1), _r3 = __shfl_down(vv[3], 1);          \
    if (lane == 63) { _r0 = 0.f; _r1 = 0.f; _r2 = 0.f; _r3 = 0.f; }          \
    float _t = (h3in) + _r0 - (l7in); h[0] = _t;                             \
    _t += _r1 - vv[0]; h[1] = _t;                                            \
    _t += _r2 - vv[1]; h[2] = _t;                                            \
    _t += _r3 - vv[2]; h[3] = _t;                                            \
} while (0)

#define CC4(h0a, h1a, h2a, h3a, h4a) do {                                    \
    _Pragma("unroll")                                                        \
    for (int _c = 0; _c < 4; ++_c) {                                         \
        float _Is = h0a[_c], _Js = h1a[_c];                                  \
        float _u  = _Is * inv81;                                             \
        float _cr = h4a[_c] - _u * _Js;                                      \
        float _Iv = h2a[_c] - _u * _Is;                                      \
        float _Jv = h3a[_c] - (_Js * inv81) * _Js;                           \
        cc_acc += (_cr * _cr) * __builtin_amdgcn_rcpf(_Iv * _Jv + 1e-6f);    \
    }                                                                        \
} while (0)

#define EPI() do {                                                           \
    float h0[4], h1[4], h2[4], h3[4], h4[4];                                 \
    float s0, s1, s2, s3, s4;                                                \
    HLO(v0, h0, s0); HLO(v1, h1, s1); HLO(v2, h2, s2);                       \
    HLO(v3, h3, s3); HLO(v4, h4, s4);                                        \
    CC4(h0, h1, h2, h3, h4);                                                 \
    float e0 = h0[3], e1 = h1[3], e2 = h2[3], e3 = h3[3], e4 = h4[3];        \
    HHI(v0, e0, s0, h0); HHI(v1, e1, s1, h1); HHI(v2, e2, s2, h2);           \
    HHI(v3, e3, s3, h3); HHI(v4, e4, s4, h4);                                \
    CC4(h0, h1, h2, h3, h4);                                                 \
} while (0)

// One output row: add new bottom row, epilogue, drop top row (register-
// resident since its load), optionally load a future row into freed slot.
#define STEPL(AB, SB, DR) do { PADD(AB); EPI(); PSUB(SB); LOADR(SB, DR); } while (0)
#define STEPN(AB, SB)     do { PADD(AB); EPI(); PSUB(SB); } while (0)

__global__ __launch_bounds__(NT, 1)
void ncc_main(const float* __restrict__ I, const float* __restrict__ J,
              float* __restrict__ partials) {
    const int lane = threadIdx.x & 63;

    // XCD swizzle: each XCD gets a contiguous band range (halo rows in L2).
    const int nblk = gridDim.x;            // 1024, divisible by 8
    const int g = (blockIdx.x & 7) * (nblk >> 3) + (blockIdx.x >> 3);

    const int b    = g >> 5;               // g / NBANDS
    const int band = g & (NBANDS - 1);
    const int y0   = band * BH;
    const float* Ip = I + (size_t)b * (H * W);
    const float* Jp = J + (size_t)b * (H * W);
    const int x0 = lane * 8;

    float v0[8], v1[8], v2[8], v3[8], v4[8];
    #pragma unroll
    for (int k = 0; k < 8; ++k) { v0[k]=0.f; v1[k]=0.f; v2[k]=0.f; v3[k]=0.f; v4[k]=0.f; }

    float cc_acc = 0.f;
    const float inv81 = 1.f / 81.f;

    DECLBUF(B0); DECLBUF(B1); DECLBUF(B2); DECLBUF(B3); DECLBUF(B4);
    DECLBUF(B5); DECLBUF(B6); DECLBUF(B7); DECLBUF(B8); DECLBUF(B9);

    // Prologue: issue 10 rows' loads back-to-back (rows y0-4 .. y0+5).
    LOADR(B0, -4); LOADR(B1, -3); LOADR(B2, -2); LOADR(B3, -1);
    LOADR(B4,  0); LOADR(B5,  1); LOADR(B6,  2); LOADR(B7,  3);
    LOADR(B8,  4); LOADR(B9,  5);

    // Prime vertical window with rows y0-4 .. y0+3.
    PADD(B0); PADD(B1); PADD(B2); PADD(B3);
    PADD(B4); PADD(B5); PADD(B6); PADD(B7);

    // 16 output rows. Slot of row r (k=r+4): k%10. Sub slot == next load slot.
    STEPL(B8, B0,  6);   // i=0 : +row4  -row-4  load row6
    STEPL(B9, B1,  7);   // i=1
    STEPL(B0, B2,  8);   // i=2
    STEPL(B1, B3,  9);   // i=3
    STEPL(B2, B4, 10);   // i=4
    STEPL(B3, B5, 11);   // i=5
    STEPL(B4, B6, 12);   // i=6
    STEPL(B5, B7, 13);   // i=7
    STEPL(B6, B8, 14);   // i=8
    STEPL(B7, B9, 15);   // i=9
    STEPL(B8, B0, 16);   // i=10
    STEPL(B9, B1, 17);   // i=11
    STEPL(B0, B2, 18);   // i=12
    STEPL(B1, B3, 19);   // i=13
    STEPN(B2, B4);       // i=14
    STEPN(B3, B5);       // i=15

    // Single-wave block: shuffle reduce, lane 0 writes the partial.
    #pragma unroll
    for (int off = 32; off > 0; off >>= 1)
        cc_acc += __shfl_down(cc_acc, off, 64);
    if (lane == 0) partials[blockIdx.x] = cc_acc;
}

__global__ __launch_bounds__(256)
void ncc_finish(const float* __restrict__ partials, float* __restrict__ out,
                int n, float inv_total) {
    float v = 0.f;
    for (int i = threadIdx.x; i < n; i += blockDim.x) v += partials[i];
    #pragma unroll
    for (int off = 32; off > 0; off >>= 1)
        v += __shfl_down(v, off, 64);
    __shared__ float wsum[4];
    if ((threadIdx.x & 63) == 0) wsum[threadIdx.x >> 6] = v;
    __syncthreads();
    if (threadIdx.x == 0) {
        float t = (wsum[0] + wsum[1]) + (wsum[2] + wsum[3]);
        out[0] = 1.0f - t * inv_total;
    }
}

extern "C" void kernel_launch(void* const* d_in, const int* in_sizes, int n_in,
                              void* d_out, int out_size, void* d_ws, size_t ws_size,
                              hipStream_t stream) {
    const float* I = (const float*)d_in[0];   // predict
    const float* J = (const float*)d_in[1];   // target
    float* out = (float*)d_out;
    float* partials = (float*)d_ws;           // nblocks floats (4 KB)

    const int n = in_sizes[0];                // B*1*H*W
    const int B = n / (H * W);
    const int nblocks = B * NBANDS;           // 1024 for B=32

    ncc_main<<<nblocks, NT, 0, stream>>>(I, J, partials);
    ncc_finish<<<1, 256, 0, stream>>>(partials, out, nblocks, 1.0f / (float)n);
}